// Round 6
// baseline (222.856 us; speedup 1.0000x reference)
//
#include <hip/hip_runtime.h>
#include <math.h>

// Problem constants (B=4, S=4096, D=2048, E=64, K=2)
#define BS_TOT 16384
#define DDIM   2048
#define NEXP   64
#define TOPK   2

#define MROWS  128               // rows per gemm block
#define NKC    8                 // split-K chunks
#define KC     (DDIM / NKC)      // 256 k per chunk
#define NTL    (KC / 32)         // 8 k-tiles (32 k) per chunk

typedef _Float16 half8   __attribute__((ext_vector_type(8)));
typedef float    floatx4 __attribute__((ext_vector_type(4)));

// ---------------------------------------------------------------------------
// Pre-pass (layout proven R4/R5): W [D][E] fp32 -> fragment-major hi/lo fp16
// (lo scaled 2048). halfs index: t*4096 + f*1024 + h*512 + lane*8 + j where
//   element = {hi,lo}( W[k = t*32 + (lane>>4)*8 + j][e = f*16 + (lane&15)] )
// Also zeroes the 4 MB logits accumulator (scores region of out).
// ---------------------------------------------------------------------------
__global__ __launch_bounds__(64)
void wsplit_kernel(const float* __restrict__ W, _Float16* __restrict__ wint,
                   float* __restrict__ logits)
{
    const int b = blockIdx.x;            // 0..255 : t = b>>2, f = b&3
    const int t = b >> 2, f = b & 3;
    const int lane = threadIdx.x;        // one wave
    const int rr = lane & 15, kg = lane >> 4;
    half8 vh, vl;
#pragma unroll
    for (int j = 0; j < 8; ++j) {
        const float v = W[(size_t)(t * 32 + kg * 8 + j) * NEXP + f * 16 + rr];
        const _Float16 h = (_Float16)v;
        vh[j] = h;
        vl[j] = (_Float16)((v - (float)h) * 2048.0f);
    }
    *(half8*)(wint + (size_t)t * 4096 + f * 1024 +       lane * 8) = vh;
    *(half8*)(wint + (size_t)t * 4096 + f * 1024 + 512 + lane * 8) = vl;

    // zero logits: 1M floats / 16384 threads = 16 float4 each, coalesced
    const int gid = b * 64 + lane;
    floatx4* lp = (floatx4*)logits;
#pragma unroll
    for (int i = 0; i < 16; ++i)
        lp[gid + i * 16384] = (floatx4){0.f, 0.f, 0.f, 0.f};
}

// ---------------------------------------------------------------------------
// GEMM: 1024 blocks (128 m x 8 kc) x 256 thr (4 waves). Block owns 128 rows x
// 256 k x all 64 experts. W slab (64 KB hi/lo f16, fragment-major) staged to
// LDS ONCE (16 linear global_load_lds + 1 barrier). K-loop: fully unrolled,
// ZERO barriers / LDS writes / manual waits — 3-slot A register ring issued
// 2 tiles ahead (static idx, sched_barrier-pinned), conflict-free contiguous
// ds_read_b128 for B, 24 MFMA/tile, 3-pass hi/lo fp16 (err ~1e-6 on logits).
// Partials deposited via fp32 atomicAdd into zeroed logits (split-K sum).
// Frag maps (HW-proven R1/R5): A row=lane&15, k=(lane>>4)*8+j; B col=lane&15;
// D col=lane&15, row=(lane>>4)*4+reg.
// ---------------------------------------------------------------------------
__global__ __launch_bounds__(256, 2)
void gemm_kernel(const float* __restrict__ x, const _Float16* __restrict__ wint,
                 float* __restrict__ logits)
{
    __shared__ _Float16 bsl[32768];      // 64 KB B slab

    const int tid  = threadIdx.x;
    const int lane = tid & 63;
    const int wv   = __builtin_amdgcn_readfirstlane(tid >> 6);  // 0..3
    const int mB   = blockIdx.x >> 3;    // 0..127
    const int kc   = blockIdx.x & 7;     // 0..7
    const int rr   = lane & 15, kg = lane >> 4;

    // ---- stage B slab: pure linear 64 KB copy from wint (L2-resident) ----
    {
        const char* sp = (const char*)(wint + (size_t)kc * (NTL * 4096))
                         + wv * 1024 + lane * 16;          // per-lane source
        char* dp = (char*)bsl + wv * 1024;                 // wave-uniform dest
#pragma unroll
        for (int i = 0; i < 16; ++i)
            __builtin_amdgcn_global_load_lds(
                (const __attribute__((address_space(1))) unsigned int*)(sp + i * 4096),
                (__attribute__((address_space(3))) unsigned int*)(dp + i * 4096),
                16, 0, 0);
    }

    // ---- A pointers: wave owns rows [wv*32, wv*32+32) of the m-block ----
    const float* xq0 = x + (size_t)(mB * MROWS + wv * 32 + rr) * DDIM + kc * KC + kg * 8;
    const float* xq1 = xq0 + (size_t)16 * DDIM;

    floatx4 gA[3][4];                    // 3-slot ring, 2 tiles in flight
#define ISSUE_A(tl) do { \
        gA[(tl) % 3][0] = *(const floatx4*)(xq0 + (tl) * 32);     \
        gA[(tl) % 3][1] = *(const floatx4*)(xq0 + (tl) * 32 + 4); \
        gA[(tl) % 3][2] = *(const floatx4*)(xq1 + (tl) * 32);     \
        gA[(tl) % 3][3] = *(const floatx4*)(xq1 + (tl) * 32 + 4); } while (0)

    ISSUE_A(0); ISSUE_A(1);
    // drain the 16 stage loads (8 A-loads may stay outstanding), then sync
    asm volatile("s_waitcnt vmcnt(8)\n\ts_barrier" ::: "memory");

    floatx4 acc[2][4], accl[2][4];       // [m-tile][e-quarter]
#pragma unroll
    for (int mt = 0; mt < 2; ++mt)
#pragma unroll
        for (int ff = 0; ff < 4; ++ff) {
            acc[mt][ff]  = (floatx4){0.f, 0.f, 0.f, 0.f};
            accl[mt][ff] = acc[mt][ff];
        }

#pragma unroll
    for (int tl = 0; tl < NTL; ++tl) {
        if (tl + 2 < NTL) ISSUE_A(tl + 2);          // keep 2 tiles in flight
        __builtin_amdgcn_sched_barrier(0);          // pin issue point
        // ---- cvt A(tl): fp32 -> f16 hi / scaled-lo (counted vmcnt wait) ----
        half8 ah0, al0, ah1, al1;
#pragma unroll
        for (int i = 0; i < 4; ++i) {
            _Float16 h; float v;
            v = gA[tl % 3][0][i]; h = (_Float16)v; ah0[i]     = h; al0[i]     = (_Float16)((v - (float)h) * 2048.0f);
            v = gA[tl % 3][1][i]; h = (_Float16)v; ah0[4 + i] = h; al0[4 + i] = (_Float16)((v - (float)h) * 2048.0f);
            v = gA[tl % 3][2][i]; h = (_Float16)v; ah1[i]     = h; al1[i]     = (_Float16)((v - (float)h) * 2048.0f);
            v = gA[tl % 3][3][i]; h = (_Float16)v; ah1[4 + i] = h; al1[4 + i] = (_Float16)((v - (float)h) * 2048.0f);
        }
        // ---- B from resident LDS slab + 24 MFMA ----
#pragma unroll
        for (int ff = 0; ff < 4; ++ff) {
            const half8 bh = *(const half8*)&bsl[tl * 4096 + ff * 1024 +       lane * 8];
            const half8 bl = *(const half8*)&bsl[tl * 4096 + ff * 1024 + 512 + lane * 8];
            acc[0][ff]  = __builtin_amdgcn_mfma_f32_16x16x32_f16(ah0, bh, acc[0][ff],  0, 0, 0);
            accl[0][ff] = __builtin_amdgcn_mfma_f32_16x16x32_f16(al0, bh, accl[0][ff], 0, 0, 0);
            accl[0][ff] = __builtin_amdgcn_mfma_f32_16x16x32_f16(ah0, bl, accl[0][ff], 0, 0, 0);
            acc[1][ff]  = __builtin_amdgcn_mfma_f32_16x16x32_f16(ah1, bh, acc[1][ff],  0, 0, 0);
            accl[1][ff] = __builtin_amdgcn_mfma_f32_16x16x32_f16(al1, bh, accl[1][ff], 0, 0, 0);
            accl[1][ff] = __builtin_amdgcn_mfma_f32_16x16x32_f16(ah1, bl, accl[1][ff], 0, 0, 0);
        }
    }
#undef ISSUE_A

    // ---- deposit split-K partials: row = base + mt*16 + kg*4 + r, e = ff*16+rr
    const float inv = 1.0f / 2048.0f;
    const int rbase = mB * MROWS + wv * 32 + kg * 4;
#pragma unroll
    for (int mt = 0; mt < 2; ++mt)
#pragma unroll
        for (int ff = 0; ff < 4; ++ff)
#pragma unroll
            for (int r = 0; r < 4; ++r)
                atomicAdd(logits + (size_t)(rbase + mt * 16 + r) * NEXP + ff * 16 + rr,
                          acc[mt][ff][r] + accl[mt][ff][r] * inv);
}

// ---------------------------------------------------------------------------
// Epilogue: 512 blocks x 256 thr; each wave handles 8 rows. Reads summed
// logits from the scores region, adds bias + noise, proven softmax/top-2
// (verbatim logic from all passing rounds), overwrites scores in place
// (each cell read+written by exactly one thread).
// ---------------------------------------------------------------------------
__global__ __launch_bounds__(256)
void epilogue_kernel(const float* __restrict__ bias, const float* __restrict__ noise,
                     float* __restrict__ out)
{
    const int tid  = threadIdx.x;
    const int lane = tid & 63;
    const int wv   = tid >> 6;
    const int row0 = blockIdx.x * 32;

    float* const scores_out = out + 2 * BS_TOT * TOPK;   // also the logits buf
    float* const iout       = out + BS_TOT * TOPK;
    const float blane = bias[lane];

#pragma unroll
    for (int j = 0; j < 8; ++j) {
        const int r2 = row0 + wv * 8 + j;
        const float v = scores_out[(size_t)r2 * NEXP + lane] + blane
                      + 0.1f * noise[(size_t)r2 * NEXP + lane];

        float m = v;
#pragma unroll
        for (int off = 1; off < 64; off <<= 1) m = fmaxf(m, __shfl_xor(m, off));
        const float p = __expf(v - m);
        float s = p;
#pragma unroll
        for (int off = 1; off < 64; off <<= 1) s += __shfl_xor(s, off);
        const float sc = p * (1.0f / s);

        scores_out[(size_t)r2 * NEXP + lane] = sc;   // 256B coalesced

        // top-2 across 64 lanes on logits (order-identical to scores),
        // ties -> lower index (matches jax.lax.top_k).
        float a1 = v, a2 = -INFINITY;
        int   i1 = lane, i2 = 0x7fffffff;
#pragma unroll
        for (int off = 1; off < 64; off <<= 1) {
            const float o1 = __shfl_xor(a1, off), o2 = __shfl_xor(a2, off);
            const int  oi1 = __shfl_xor(i1, off), oi2 = __shfl_xor(i2, off);
            if (o1 > a1 || (o1 == a1 && oi1 < i1)) {
                if (a1 > o2 || (a1 == o2 && i1 < oi2)) { a2 = a1; i2 = i1; }
                else                                   { a2 = o2; i2 = oi2; }
                a1 = o1; i1 = oi1;
            } else {
                if (o1 > a2 || (o1 == a2 && oi1 < i2)) { a2 = o1; i2 = oi1; }
            }
        }
        const float s1 = __shfl(sc, i1);   // bitwise == scores entries
        const float s2 = __shfl(sc, i2);
        if (lane == 0) {
            out[(size_t)r2 * TOPK + 0]  = s1;
            out[(size_t)r2 * TOPK + 1]  = s2;
            iout[(size_t)r2 * TOPK + 0] = (float)i1;
            iout[(size_t)r2 * TOPK + 1] = (float)i2;
        }
    }
}

extern "C" void kernel_launch(void* const* d_in, const int* in_sizes, int n_in,
                              void* d_out, int out_size, void* d_ws, size_t ws_size,
                              hipStream_t stream)
{
    const float* x     = (const float*)d_in[0];
    const float* W     = (const float*)d_in[1];
    const float* bias  = (const float*)d_in[2];
    const float* noise = (const float*)d_in[3];
    float* out = (float*)d_out;
    (void)in_sizes; (void)n_in; (void)out_size; (void)ws_size;

    _Float16* wint = (_Float16*)d_ws;             // 512 KB fragment-major hi/lo
    float* logits  = out + 2 * BS_TOT * TOPK;     // scores region doubles as acc

    hipLaunchKernelGGL(wsplit_kernel, dim3(256), dim3(64), 0, stream,
                       W, wint, logits);
    hipLaunchKernelGGL(gemm_kernel, dim3((BS_TOT / MROWS) * NKC), dim3(256), 0,
                       stream, x, wint, logits);
    hipLaunchKernelGGL(epilogue_kernel, dim3(BS_TOT / 32), dim3(256), 0, stream,
                       bias, noise, out);
}